// Round 9
// baseline (177.129 us; speedup 1.0000x reference)
//
#include <hip/hip_runtime.h>
#include <math.h>

#define T_STEPS 9
#define D_IN    512
#define HID     64
#define G4      256   // 4*HID
#define BPB     4     // batches per block
#define ROWS    36    // real tile rows = BPB * T_STEPS (tiles 0..2, rows 36-47 pad)

typedef short  short8 __attribute__((ext_vector_type(8)));
typedef float  f32x4  __attribute__((ext_vector_type(4)));
typedef unsigned int uint;
typedef unsigned short ushort;

// ---------------------------------------------------------------------------
__device__ __forceinline__ ushort f2bf(float f) {
    uint u = __float_as_uint(f);
    u = (u + 0x7FFFu + ((u >> 16) & 1u)) >> 16;   // RNE
    return (ushort)u;
}
__device__ __forceinline__ float fsig(float x) {
    return 1.0f / (1.0f + __expf(-x));
}
__device__ __forceinline__ float ftanh(float x) {
    float t = __expf(-2.0f * fabsf(x));
    float r = (1.0f - t) / (1.0f + t);
    return copysignf(r, x);
}
__device__ __forceinline__ short8 cvt8(float4 a, float4 b) {
    union { uint4 u; short8 s; } r;
    r.u.x = f2bf(a.x) | ((uint)f2bf(a.y) << 16);
    r.u.y = f2bf(a.z) | ((uint)f2bf(a.w) << 16);
    r.u.z = f2bf(b.x) | ((uint)f2bf(b.y) << 16);
    r.u.w = f2bf(b.z) | ((uint)f2bf(b.w) << 16);
    return r.s;
}

// ---------------------------------------------------------------------------
// Prepass: weights -> bf16 fragment-exact layouts.
// WxT: [k0(16)][qk(4)][n(256)][j(8)]   k = k0*32+qk*8+j   (131072 elems, 256 KB)
// WhT: [kq(8)][n(256)][j(8)]           k = kq*8+j         ( 16384 elems,  32 KB)
__global__ __launch_bounds__(256)
void prep_w(const float* __restrict__ kern, ushort* __restrict__ wxT,
            ushort* __restrict__ whT)
{
    int i = blockIdx.x * 256 + threadIdx.x;
    if (i < 131072) {
        int j  = i & 7;
        int n  = (i >> 3) & 255;
        int qk = (i >> 11) & 3;
        int k0 = i >> 13;
        int k  = k0 * 32 + qk * 8 + j;
        wxT[i] = f2bf(kern[(size_t)k * G4 + n]);
    } else {
        int i2 = i - 131072;
        int j  = i2 & 7;
        int n  = (i2 >> 3) & 255;
        int kq = i2 >> 11;
        whT[i2] = f2bf(kern[(size_t)(D_IN + kq * 8 + j) * G4 + n]);
    }
}

// ---------------------------------------------------------------------------
// R9: max-occupancy fused LSTM. BPB=4, 1024 blocks, LDS = 2 KB (sH only),
// __launch_bounds__(256,4) -> <=128 VGPR -> 4 blocks/CU = 16 waves/CU.
// Phase 1: A-fragments loaded DIRECTLY from global x (two float4/lane;
// each 128B line consumed once by one wave) — no staging, no barriers.
// Tile row m = s*4 + b  (s=step, b=batch): acc[itile][g] C-row quad*4+r
// holds (step = itile*4+quad, batch = r). Phase 2: 4-phase parity —
// step s handled by quad s&3; c handoff via shfl from quad-1; h via sH
// rows ((s+1)&3)*4+b in A-operand layout.
__global__ __launch_bounds__(256, 4)
void lstm_fused(const float* __restrict__ x, const ushort* __restrict__ wxT,
                const ushort* __restrict__ whT, const float* __restrict__ bias,
                float* __restrict__ out)
{
    __shared__ ushort sH[8 * 16 * 8];   // 2 KB [kq(8)][m(16)][j(8)]

    const int t = threadIdx.x;
    const int w = t >> 6, l = t & 63;
    const int lane15 = l & 15, quad = l >> 4;
    const int u = w * 16 + lane15;

    ((uint2*)sH)[t] = (uint2){0u, 0u};   // h_{-1} = 0 (all 4 phase rows)

    // ---- per-lane x row byte-offsets for the 3 m-tiles
    // m = i*16 + lane15 -> s' = i*4 + (lane15>>2), b' = lane15&3,
    // x row = b'*9 + s'.  Tile 2 real only for lane15<4 (clamp, rows unread).
    const char* xb = (const char*)(x + (size_t)blockIdx.x * (BPB * T_STEPS * D_IN));
    const int sq = lane15 >> 2, bq = lane15 & 3;
    int vo[3];
    vo[0] = (bq * 9 + sq) * 2048 + quad * 32;
    vo[1] = (bq * 9 + 4 + sq) * 2048 + quad * 32;
    vo[2] = ((lane15 < 4) ? (lane15 * 9 + 8) : 35) * 2048 + quad * 32;

    f32x4 acc[3][4];
    #pragma unroll
    for (int i = 0; i < 3; ++i)
        #pragma unroll
        for (int g = 0; g < 4; ++g)
            acc[i][g] = (f32x4){0.f, 0.f, 0.f, 0.f};

    // ---- prologue: x(0) + bF(0)
    float4 rx[3][2];
    #pragma unroll
    for (int i = 0; i < 3; ++i) {
        rx[i][0] = *(const float4*)(xb + vo[i]);
        rx[i][1] = *(const float4*)(xb + vo[i] + 16);
    }
    short8 bF[4];
    #pragma unroll
    for (int g = 0; g < 4; ++g)
        bF[g] = *(const short8*)&wxT[(size_t)(quad * 256 + g * 64 + u) * 8];

    // =============  Phase 1: barrier-free K-loop  =========================
    #pragma unroll
    for (int k = 0; k < 16; ++k) {
        short8 aF[3];
        #pragma unroll
        for (int i = 0; i < 3; ++i) aF[i] = cvt8(rx[i][0], rx[i][1]);   // waits x(k)
        if (k < 15) {   // issue x(k+1) (regs freed by cvt)
            #pragma unroll
            for (int i = 0; i < 3; ++i) {
                rx[i][0] = *(const float4*)(xb + vo[i] + (k + 1) * 128);
                rx[i][1] = *(const float4*)(xb + vo[i] + (k + 1) * 128 + 16);
            }
        }
        #pragma unroll
        for (int i = 0; i < 3; ++i)
            #pragma unroll
            for (int g = 0; g < 4; ++g)
                acc[i][g] = __builtin_amdgcn_mfma_f32_16x16x32_bf16(aF[i], bF[g], acc[i][g], 0, 0, 0);
        if (k < 15) {   // bF(k+1): L1-hot (shared by all 16 waves on the CU)
            #pragma unroll
            for (int g = 0; g < 4; ++g)
                bF[g] = *(const short8*)&wxT[(size_t)(((k + 1) * 4 + quad) * 256 + g * 64 + u) * 8];
        }
    }

    // =======================  Phase 2: recurrence  ========================
    short8 whF[4][2];
    #pragma unroll
    for (int g = 0; g < 4; ++g)
        #pragma unroll
        for (int kh = 0; kh < 2; ++kh)
            whF[g][kh] = *(const short8*)&whT[(size_t)((kh * 4 + quad) * 256 + g * 64 + u) * 8];

    float bia[4];
    bia[0] = bias[u];
    bia[1] = bias[64 + u];
    bia[2] = bias[128 + u] + 1.0f;       // FORGET_BIAS folded
    bia[3] = bias[192 + u];

    float cst[4] = {0.f, 0.f, 0.f, 0.f};
    const int b0 = blockIdx.x * BPB;
    const int srcl = (((quad + 3) & 3) << 4) + lane15;   // prev-phase lane

    __syncthreads();   // sH zero-init visible (phase 1 had no barriers)

    #pragma unroll                         // static acc[] indices (R5 lesson)
    for (int s = 0; s < T_STEPS; ++s) {
        const int  itile = s >> 2;
        const int  phase = s & 3;
        const bool active = (quad == phase);

        f32x4 g4[4];
        #pragma unroll
        for (int g = 0; g < 4; ++g)
            #pragma unroll
            for (int r = 0; r < 4; ++r)
                g4[g][r] = acc[itile][g][r] + bia[g];

        // h_{s-1} at A rows phase*4+b (written last step); other rows stale,
        // feed only inactive C rows
        short8 aFh[2];
        #pragma unroll
        for (int kh = 0; kh < 2; ++kh)
            aFh[kh] = *(const short8*)&sH[((kh * 4 + quad) * 16 + lane15) * 8];

        #pragma unroll
        for (int g = 0; g < 4; ++g)
            #pragma unroll
            for (int kh = 0; kh < 2; ++kh)
                g4[g] = __builtin_amdgcn_mfma_f32_16x16x32_bf16(aFh[kh], whF[g][kh], g4[g], 0, 0, 0);

        __syncthreads();   // all sH reads of this step done

        const int wrow = ((s + 1) & 3) * 4;   // rows for h_s = next phase
        #pragma unroll
        for (int r = 0; r < 4; ++r) {
            float cp = __shfl(cst[r], srcl);   // c_{s-1} from prev-phase quad
            if (active) {
                float ii = fsig(g4[0][r]);
                float jj = ftanh(g4[1][r]);
                float ff = fsig(g4[2][r]);
                float oo = fsig(g4[3][r]);
                float c  = ff * cp + ii * jj;
                cst[r] = c;
                float h = oo * ftanh(c);
                out[((size_t)(b0 + r) * T_STEPS + s) * HID + u] = h;
                sH[((u >> 3) * 16 + wrow + r) * 8 + (u & 7)] = f2bf(h);
            }
        }
        __syncthreads();   // h_s visible before next step's reads
    }
}

// ---------------------------------------------------------------------------
extern "C" void kernel_launch(void* const* d_in, const int* in_sizes, int n_in,
                              void* d_out, int out_size, void* d_ws, size_t ws_size,
                              hipStream_t stream)
{
    const float* x    = (const float*)d_in[0];
    const float* kern = (const float*)d_in[1];
    const float* bias = (const float*)d_in[2];
    float* out = (float*)d_out;

    const int B = in_sizes[0] / (T_STEPS * D_IN);   // 4096

    ushort* wxT = (ushort*)d_ws;                    // 256 KB
    ushort* whT = (ushort*)((char*)d_ws + 262144);  // 32 KB

    prep_w<<<576, 256, 0, stream>>>(kern, wxT, whT);
    lstm_fused<<<B / BPB, 256, 0, stream>>>(x, wxT, whT, bias, out);
}